// Round 1
// baseline (6354.623 us; speedup 1.0000x reference)
//
#include <hip/hip_runtime.h>
#include <hip/hip_bf16.h>
#include <math.h>

// Problem constants (B=2, T=2048, C=2048, 16 heads, 4 KV heads, HD=128)
#define NB 2
#define T_SEQ 2048
#define C_DIM 2048
#define NH 16
#define NKV 4
#define HD 128
#define KV_DIM (NKV * HD)   // 512
#define M_ROWS (NB * T_SEQ) // 4096

__device__ __forceinline__ float wave_reduce_sum(float v) {
#pragma unroll
  for (int off = 32; off > 0; off >>= 1) v += __shfl_xor(v, off, 64);
  return v;
}
__device__ __forceinline__ float wave_reduce_max(float v) {
#pragma unroll
  for (int off = 32; off > 0; off >>= 1) v = fmaxf(v, __shfl_xor(v, off, 64));
  return v;
}

// ---------------------------------------------------------------------------
// RoPE cos/sin tables: [T][64] each. theta = 500000.
// ---------------------------------------------------------------------------
__global__ void rope_tables(float* __restrict__ cost, float* __restrict__ sint) {
  int t = blockIdx.x;
  int i = threadIdx.x; // 0..63
  float inv_freq = powf(500000.0f, -(float)i / 64.0f);
  float ang = (float)t * inv_freq;
  cost[t * 64 + i] = cosf(ang);
  sint[t * 64 + i] = sinf(ang);
}

// ---------------------------------------------------------------------------
// C[M][N] = A[M][K] * W[N][K]^T  (Linear with weight [out,in])
// fp32 tiled: 128x128 block tile, BK=8, 256 threads, 8x8 per-thread tile.
// LDS stored K-major (As[kk][row]) so fragment reads are ds_read_b128.
// M,N,K all divisible by tile dims for this problem.
// ---------------------------------------------------------------------------
__global__ __launch_bounds__(256) void gemm_nt_f32(
    const float* __restrict__ A, const float* __restrict__ W,
    float* __restrict__ C, int M, int N, int K) {
  __shared__ float As[8][128];
  __shared__ float Bs[8][128];
  int tid = threadIdx.x;
  int bx = blockIdx.x, by = blockIdx.y;
  int tx = tid & 15;       // 0..15 -> col group
  int ty = tid >> 4;       // 0..15 -> row group
  int lr = tid >> 1;       // 0..127 (tile row to load)
  int lc = (tid & 1) * 4;  // 0 or 4 (k offset to load)

  const float* Arow = A + (size_t)(by * 128 + lr) * K + lc;
  const float* Wrow = W + (size_t)(bx * 128 + lr) * K + lc;

  float acc[8][8];
#pragma unroll
  for (int i = 0; i < 8; ++i)
#pragma unroll
    for (int j = 0; j < 8; ++j) acc[i][j] = 0.f;

  for (int k0 = 0; k0 < K; k0 += 8) {
    float4 av = *(const float4*)(Arow + k0);
    float4 bv = *(const float4*)(Wrow + k0);
    __syncthreads(); // protect previous iteration's reads
    As[lc + 0][lr] = av.x; As[lc + 1][lr] = av.y;
    As[lc + 2][lr] = av.z; As[lc + 3][lr] = av.w;
    Bs[lc + 0][lr] = bv.x; Bs[lc + 1][lr] = bv.y;
    Bs[lc + 2][lr] = bv.z; Bs[lc + 3][lr] = bv.w;
    __syncthreads();
#pragma unroll
    for (int kk = 0; kk < 8; ++kk) {
      float a[8], b[8];
      *(float4*)&a[0] = *(const float4*)&As[kk][ty * 8];
      *(float4*)&a[4] = *(const float4*)&As[kk][ty * 8 + 4];
      *(float4*)&b[0] = *(const float4*)&Bs[kk][tx * 8];
      *(float4*)&b[4] = *(const float4*)&Bs[kk][tx * 8 + 4];
#pragma unroll
      for (int i = 0; i < 8; ++i)
#pragma unroll
        for (int j = 0; j < 8; ++j) acc[i][j] = fmaf(a[i], b[j], acc[i][j]);
    }
  }

#pragma unroll
  for (int i = 0; i < 8; ++i) {
    float* Crow = C + (size_t)(by * 128 + ty * 8 + i) * N + bx * 128 + tx * 8;
    *(float4*)(Crow + 0) = *(float4*)&acc[i][0];
    *(float4*)(Crow + 4) = *(float4*)&acc[i][4];
  }
}

// ---------------------------------------------------------------------------
// Fused per-head RMSNorm + RoPE, in place on [B*T][nheads*128].
// One wave per (bt, head) row. Lane l owns dims l and l+64 (the rotate pair).
// ---------------------------------------------------------------------------
__global__ __launch_bounds__(256) void norm_rope(
    float* __restrict__ X, const float* __restrict__ w,
    const float* __restrict__ cost, const float* __restrict__ sint, int nheads) {
  int wid = (blockIdx.x * blockDim.x + threadIdx.x) >> 6;
  int lane = threadIdx.x & 63;
  int h = wid % nheads;
  int bt = wid / nheads;
  int t = bt % T_SEQ;
  float* row = X + (size_t)bt * (nheads * HD) + h * HD;
  float x1 = row[lane];
  float x2 = row[lane + 64];
  float ss = wave_reduce_sum(x1 * x1 + x2 * x2);
  float r = rsqrtf(ss * (1.0f / 128.0f) + 1e-6f);
  x1 = x1 * r * w[lane];
  x2 = x2 * r * w[lane + 64];
  float c = cost[t * 64 + lane];
  float s = sint[t * 64 + lane];
  row[lane]      = x1 * c - x2 * s;
  row[lane + 64] = x2 * c + x1 * s;
}

// ---------------------------------------------------------------------------
// Causal GQA flash attention, fp32.
// Q/O: [B*T][NH*128]; K/V: [B*T][NKV*128] (post norm+rope K).
// One wave per (b, h, t) query row; lane j handles key block_base+j for QK^T,
// online softmax across the 64 lane scores, shfl-broadcast PV accumulate.
// ---------------------------------------------------------------------------
__global__ __launch_bounds__(256) void attn_f32(
    const float* __restrict__ Q, const float* __restrict__ K,
    const float* __restrict__ V, float* __restrict__ O) {
  __shared__ float qs[4][HD];
  int lane = threadIdx.x & 63;
  int wslot = threadIdx.x >> 6;
  int gw = blockIdx.x * 4 + wslot;  // (b*NH + h)*T + t
  int t = gw % T_SEQ;
  int bh = gw / T_SEQ;
  int h = bh % NH;
  int b = bh / NH;
  int kvh = h >> 2;  // h / N_REP, N_REP = 4

  const float* qrow = Q + ((size_t)(b * T_SEQ + t)) * C_DIM + h * HD;
  qs[wslot][lane] = qrow[lane];
  qs[wslot][lane + 64] = qrow[lane + 64];
  __syncthreads();

  const float scale = 0.08838834764831845f; // 1/sqrt(128)
  float m = -INFINITY, l = 0.f, o1 = 0.f, o2 = 0.f;
  int nkb = (t >> 6) + 1;
  const float* Kbase = K + (size_t)b * T_SEQ * KV_DIM + kvh * HD;
  const float* Vbase = V + (size_t)b * T_SEQ * KV_DIM + kvh * HD;
  const float4* qv = (const float4*)qs[wslot];

  for (int kb = 0; kb < nkb; ++kb) {
    int key = kb * 64 + lane;
    const float4* krow = (const float4*)(Kbase + (size_t)key * KV_DIM);
    float dot = 0.f;
#pragma unroll 8
    for (int d4 = 0; d4 < 32; ++d4) {
      float4 k4 = krow[d4];
      float4 q4 = qv[d4];
      dot += q4.x * k4.x + q4.y * k4.y + q4.z * k4.z + q4.w * k4.w;
    }
    dot = (key <= t) ? dot * scale : -INFINITY;

    float bmax = wave_reduce_max(dot);
    float mnew = fmaxf(m, bmax);
    float p = __expf(dot - mnew);          // masked lanes: exp(-inf)=0
    float corr = __expf(m - mnew);         // first block: exp(-inf)=0
    float psum = wave_reduce_sum(p);
    l = l * corr + psum;
    o1 *= corr;
    o2 *= corr;

    const float* vrow = Vbase + (size_t)(kb * 64) * KV_DIM;
#pragma unroll 8
    for (int j = 0; j < 64; ++j) {
      float pj = __shfl(p, j, 64);
      o1 = fmaf(pj, vrow[(size_t)j * KV_DIM + lane], o1);
      o2 = fmaf(pj, vrow[(size_t)j * KV_DIM + lane + 64], o2);
    }
    m = mnew;
  }

  float inv_l = 1.f / l;
  float* orow = O + ((size_t)(b * T_SEQ + t)) * C_DIM + h * HD;
  orow[lane] = o1 * inv_l;
  orow[lane + 64] = o2 * inv_l;
}

// ---------------------------------------------------------------------------
// Launch
// ---------------------------------------------------------------------------
extern "C" void kernel_launch(void* const* d_in, const int* in_sizes, int n_in,
                              void* d_out, int out_size, void* d_ws, size_t ws_size,
                              hipStream_t stream) {
  const float* x  = (const float*)d_in[0];
  const float* wq = (const float*)d_in[1];
  const float* wk = (const float*)d_in[2];
  const float* wv = (const float*)d_in[3];
  const float* wo = (const float*)d_in[4];
  const float* qw = (const float*)d_in[5];
  const float* kw = (const float*)d_in[6];
  float* out = (float*)d_out;

  float* ws = (float*)d_ws;
  float* qp   = ws;                                  // [4096][2048]
  float* kp   = qp + (size_t)M_ROWS * C_DIM;         // [4096][512]
  float* vp   = kp + (size_t)M_ROWS * KV_DIM;        // [4096][512]
  float* att  = vp + (size_t)M_ROWS * KV_DIM;        // [4096][2048]
  float* cost = att + (size_t)M_ROWS * C_DIM;        // [2048][64]
  float* sint = cost + (size_t)T_SEQ * 64;           // [2048][64]

  rope_tables<<<dim3(T_SEQ), dim3(64), 0, stream>>>(cost, sint);

  dim3 blk(256);
  // Projections
  gemm_nt_f32<<<dim3(C_DIM / 128, M_ROWS / 128), blk, 0, stream>>>(
      x, wq, qp, M_ROWS, C_DIM, C_DIM);
  gemm_nt_f32<<<dim3(KV_DIM / 128, M_ROWS / 128), blk, 0, stream>>>(
      x, wk, kp, M_ROWS, KV_DIM, C_DIM);
  gemm_nt_f32<<<dim3(KV_DIM / 128, M_ROWS / 128), blk, 0, stream>>>(
      x, wv, vp, M_ROWS, KV_DIM, C_DIM);

  // Per-head RMSNorm + RoPE (in place)
  norm_rope<<<dim3(M_ROWS * NH / 4), blk, 0, stream>>>(qp, qw, cost, sint, NH);
  norm_rope<<<dim3(M_ROWS * NKV / 4), blk, 0, stream>>>(kp, kw, cost, sint, NKV);

  // Causal GQA attention
  attn_f32<<<dim3(NB * NH * T_SEQ / 4), blk, 0, stream>>>(qp, kp, vp, att);

  // Output projection
  gemm_nt_f32<<<dim3(C_DIM / 128, M_ROWS / 128), blk, 0, stream>>>(
      att, wo, out, M_ROWS, C_DIM, C_DIM);
}

// Round 2
// 753.065 us; speedup vs baseline: 8.4383x; 8.4383x over previous
//
#include <hip/hip_runtime.h>
#include <math.h>

// Problem constants (B=2, T=2048, C=2048, 16 heads, 4 KV heads, HD=128)
#define NB 2
#define T_SEQ 2048
#define C_DIM 2048
#define NH 16
#define NKV 4
#define HD 128
#define KV_DIM (NKV * HD)   // 512
#define M_ROWS (NB * T_SEQ) // 4096

typedef short bf16w8 __attribute__((ext_vector_type(8)));   // MFMA A/B frag (8 bf16)
typedef float f32x4 __attribute__((ext_vector_type(4)));    // MFMA C/D frag
typedef unsigned short u16x8 __attribute__((ext_vector_type(8)));
typedef unsigned short u16x4 __attribute__((ext_vector_type(4)));

__device__ __forceinline__ unsigned short f2bf(float x) {
  union { float f; unsigned u; } v; v.f = x;
  return (unsigned short)((v.u + 0x7FFFu + ((v.u >> 16) & 1u)) >> 16);
}

__device__ __forceinline__ float wave_reduce_sum(float v) {
#pragma unroll
  for (int off = 32; off > 0; off >>= 1) v += __shfl_xor(v, off, 64);
  return v;
}

// ---------------------------------------------------------------------------
// fp32 -> bf16 bulk convert (16B stores). n8 = elems/8, sizes divisible by 8.
// ---------------------------------------------------------------------------
__global__ __launch_bounds__(256) void cvt_f32_bf16(
    const float* __restrict__ in, unsigned short* __restrict__ out, int n8) {
  int i = blockIdx.x * 256 + threadIdx.x;
  if (i >= n8) return;
  float4 a = ((const float4*)in)[i * 2];
  float4 b = ((const float4*)in)[i * 2 + 1];
  u16x8 o;
  o[0] = f2bf(a.x); o[1] = f2bf(a.y); o[2] = f2bf(a.z); o[3] = f2bf(a.w);
  o[4] = f2bf(b.x); o[5] = f2bf(b.y); o[6] = f2bf(b.z); o[7] = f2bf(b.w);
  *(u16x8*)(out + (size_t)i * 8) = o;
}

// ---------------------------------------------------------------------------
// RoPE cos/sin tables: [T][64] each. theta = 500000.
// ---------------------------------------------------------------------------
__global__ void rope_tables(float* __restrict__ cost, float* __restrict__ sint) {
  int t = blockIdx.x;
  int i = threadIdx.x; // 0..63
  float inv_freq = powf(500000.0f, -(float)i / 64.0f);
  float ang = (float)t * inv_freq;
  cost[t * 64 + i] = cosf(ang);
  sint[t * 64 + i] = sinf(ang);
}

// ---------------------------------------------------------------------------
// GEMM: C[M][N] = A[M][K] * W[N][K]^T, A/W bf16 (ushort), C fp32.
// 128x128 tile, BK=64, 4 waves (2x2), per-wave 64x64 via 4x4 mfma 16x16x32.
// LDS XOR-swizzled (granule ^ (row&7)) -> conflict-free ds_read_b128 (T2).
// ---------------------------------------------------------------------------
__global__ __launch_bounds__(256) void gemm_bt_bf16(
    const unsigned short* __restrict__ A, const unsigned short* __restrict__ W,
    float* __restrict__ C, int M, int N, int K) {
  __shared__ __align__(16) unsigned short As[128][64];
  __shared__ __align__(16) unsigned short Ws[128][64];
  int tid = threadIdx.x;
  int lane = tid & 63;
  int wid = tid >> 6;
  int wr = wid >> 1, wc = wid & 1;
  int l15 = lane & 15, l4 = lane >> 4;
  int bx = blockIdx.x, by = blockIdx.y;

  int lrow = tid >> 1;          // 0..127
  int lg0 = (tid & 1) * 4;      // granule base (8 bf16 per granule)
  int swz = lrow & 7;

  const unsigned short* Abase = A + (size_t)(by * 128 + lrow) * K + lg0 * 8;
  const unsigned short* Wbase = W + (size_t)(bx * 128 + lrow) * K + lg0 * 8;

  f32x4 zero = {0.f, 0.f, 0.f, 0.f};
  f32x4 acc[4][4];
#pragma unroll
  for (int m = 0; m < 4; ++m)
#pragma unroll
    for (int n = 0; n < 4; ++n) acc[m][n] = zero;

  for (int k0 = 0; k0 < K; k0 += 64) {
    u16x8 av[4], wv[4];
#pragma unroll
    for (int i = 0; i < 4; ++i) {
      av[i] = *(const u16x8*)(Abase + k0 + i * 8);
      wv[i] = *(const u16x8*)(Wbase + k0 + i * 8);
    }
    __syncthreads();
#pragma unroll
    for (int i = 0; i < 4; ++i) {
      int g = lg0 + i;
      *(u16x8*)&As[lrow][(g ^ swz) * 8] = av[i];
      *(u16x8*)&Ws[lrow][(g ^ swz) * 8] = wv[i];
    }
    __syncthreads();

    bf16w8 af[2][4], bw[2][4];
#pragma unroll
    for (int kk = 0; kk < 2; ++kk) {
#pragma unroll
      for (int m = 0; m < 4; ++m) {
        int r = wr * 64 + m * 16 + l15;
        int g = (kk * 4 + l4) ^ (r & 7);
        af[kk][m] = *(const bf16w8*)&As[r][g * 8];
      }
#pragma unroll
      for (int n = 0; n < 4; ++n) {
        int r = wc * 64 + n * 16 + l15;
        int g = (kk * 4 + l4) ^ (r & 7);
        bw[kk][n] = *(const bf16w8*)&Ws[r][g * 8];
      }
    }
#pragma unroll
    for (int kk = 0; kk < 2; ++kk)
#pragma unroll
      for (int m = 0; m < 4; ++m)
#pragma unroll
        for (int n = 0; n < 4; ++n)
          acc[m][n] = __builtin_amdgcn_mfma_f32_16x16x32_bf16(
              af[kk][m], bw[kk][n], acc[m][n], 0, 0, 0);
  }

#pragma unroll
  for (int m = 0; m < 4; ++m)
#pragma unroll
    for (int n = 0; n < 4; ++n)
#pragma unroll
      for (int j = 0; j < 4; ++j) {
        int row = by * 128 + wr * 64 + m * 16 + l4 * 4 + j;
        int col = bx * 128 + wc * 64 + n * 16 + l15;
        C[(size_t)row * N + col] = acc[m][n][j];
      }
}

// ---------------------------------------------------------------------------
// Per-head RMSNorm + RoPE, fp32 in -> bf16 out (scale folded for Q).
// One wave per (bt, head) row; lane l owns dims l and l+64.
// ---------------------------------------------------------------------------
__global__ __launch_bounds__(256) void norm_rope_bf16(
    const float* __restrict__ X, unsigned short* __restrict__ Y,
    const float* __restrict__ w, const float* __restrict__ cost,
    const float* __restrict__ sint, int nheads, float oscale) {
  int wid = (blockIdx.x * 256 + threadIdx.x) >> 6;
  int lane = threadIdx.x & 63;
  int h = wid % nheads;
  int bt = wid / nheads;
  int t = bt & (T_SEQ - 1);
  const float* row = X + (size_t)bt * (nheads * HD) + h * HD;
  float x1 = row[lane];
  float x2 = row[lane + 64];
  float ss = wave_reduce_sum(x1 * x1 + x2 * x2);
  float r = rsqrtf(ss * (1.0f / 128.0f) + 1e-6f);
  x1 = x1 * r * w[lane];
  x2 = x2 * r * w[lane + 64];
  float c = cost[t * 64 + lane];
  float s = sint[t * 64 + lane];
  unsigned short* yrow = Y + (size_t)bt * (nheads * HD) + h * HD;
  yrow[lane]      = f2bf((x1 * c - x2 * s) * oscale);
  yrow[lane + 64] = f2bf((x2 * c + x1 * s) * oscale);
}

// ---------------------------------------------------------------------------
// V transpose: vp fp32 [B*T][512] -> vt bf16 [(b*512 + c)][T]  (c = kvh*128+d)
// 64x64 tiles through LDS (padded) so both sides coalesce.
// ---------------------------------------------------------------------------
__global__ __launch_bounds__(256) void transpose_v(
    const float* __restrict__ Vp, unsigned short* __restrict__ Vt) {
  __shared__ float tile[64][65];
  int bt_tile = blockIdx.x;           // 0..63  (b*32 + ttile)
  int ct = blockIdx.y;                // 0..7
  int b = bt_tile >> 5;
  int t0 = (bt_tile & 31) * 64;
  int c0 = ct * 64;
  int tid = threadIdx.x;
  int r = tid >> 4;                   // 0..15
  int c4 = (tid & 15) * 4;
#pragma unroll
  for (int p = 0; p < 4; ++p) {
    int row = r + p * 16;
    float4 v = *(const float4*)&Vp[(size_t)(b * T_SEQ + t0 + row) * KV_DIM + c0 + c4];
    tile[row][c4] = v.x; tile[row][c4 + 1] = v.y;
    tile[row][c4 + 2] = v.z; tile[row][c4 + 3] = v.w;
  }
  __syncthreads();
#pragma unroll
  for (int p = 0; p < 4; ++p) {
    int drow = r + p * 16;            // local col index = output row
    int cg = c0 + drow;
    u16x4 o;
    o[0] = f2bf(tile[c4 + 0][drow]);
    o[1] = f2bf(tile[c4 + 1][drow]);
    o[2] = f2bf(tile[c4 + 2][drow]);
    o[3] = f2bf(tile[c4 + 3][drow]);
    *(u16x4*)&Vt[(size_t)(b * KV_DIM + cg) * T_SEQ + t0 + c4] = o;
  }
}

// ---------------------------------------------------------------------------
// Causal GQA flash attention, bf16 MFMA.
// Qb [B*T][2048] bf16 (pre-scaled by 1/sqrt(128)); Kb [B*T][512] bf16;
// Vt [(b*512+c)][T] bf16 transposed; Ob [B*T][2048] bf16.
// 4 waves/block, wave = 16 q-rows, KV block = 64 keys.
// ---------------------------------------------------------------------------
__global__ __launch_bounds__(256) void attn_mfma(
    const unsigned short* __restrict__ Qb, const unsigned short* __restrict__ Kb,
    const unsigned short* __restrict__ Vt, unsigned short* __restrict__ Ob) {
  __shared__ __align__(16) unsigned short pl[4][16][72];  // P staging, padded
  int lane = threadIdx.x & 63;
  int w = threadIdx.x >> 6;
  int l15 = lane & 15, l4 = lane >> 4;

  int qtile = blockIdx.x & 31;          // T/64
  int h = (blockIdx.x >> 5) & 15;
  int b = blockIdx.x >> 9;
  int kvh = h >> 2;
  int q0 = qtile * 64;

  // Q fragments (row = l15, k = kc*32 + l4*8)
  const unsigned short* qrow =
      Qb + (size_t)(b * T_SEQ + q0 + w * 16 + l15) * C_DIM + h * HD + l4 * 8;
  bf16w8 qf[4];
#pragma unroll
  for (int kc = 0; kc < 4; ++kc) qf[kc] = *(const bf16w8*)(qrow + kc * 32);

  f32x4 zero = {0.f, 0.f, 0.f, 0.f};
  f32x4 acc[8];
#pragma unroll
  for (int dn = 0; dn < 8; ++dn) acc[dn] = zero;
  float ms[4] = {-INFINITY, -INFINITY, -INFINITY, -INFINITY};
  float ls[4] = {0.f, 0.f, 0.f, 0.f};

  const unsigned short* Kbase = Kb + (size_t)(b * T_SEQ) * KV_DIM + kvh * HD + l4 * 8;
  const unsigned short* Vbase =
      Vt + ((size_t)(b * NKV + kvh) * HD + l15) * T_SEQ + l4 * 8;

  for (int kb = 0; kb <= qtile; ++kb) {
    int kbase = kb * 64;
    f32x4 s[4];
#pragma unroll
    for (int n = 0; n < 4; ++n) s[n] = zero;

    __builtin_amdgcn_s_setprio(1);
#pragma unroll
    for (int n = 0; n < 4; ++n) {
      const unsigned short* kr = Kbase + (size_t)(kbase + n * 16 + l15) * KV_DIM;
#pragma unroll
      for (int kc = 0; kc < 4; ++kc)
        s[n] = __builtin_amdgcn_mfma_f32_16x16x32_bf16(
            qf[kc], *(const bf16w8*)(kr + kc * 32), s[n], 0, 0, 0);
    }
    __builtin_amdgcn_s_setprio(0);

    if (kb == qtile) {  // diagonal block: mask key > qrow
      int qr = w * 16 + l4 * 4;
#pragma unroll
      for (int n = 0; n < 4; ++n) {
        int key = n * 16 + l15;
#pragma unroll
        for (int j = 0; j < 4; ++j)
          if (key > qr + j) s[n][j] = -INFINITY;
      }
    }

#pragma unroll
    for (int j = 0; j < 4; ++j) {
      float rm = fmaxf(fmaxf(s[0][j], s[1][j]), fmaxf(s[2][j], s[3][j]));
      rm = fmaxf(rm, __shfl_xor(rm, 1, 64));
      rm = fmaxf(rm, __shfl_xor(rm, 2, 64));
      rm = fmaxf(rm, __shfl_xor(rm, 4, 64));
      rm = fmaxf(rm, __shfl_xor(rm, 8, 64));
      float mnew = fmaxf(ms[j], rm);
      float corr = __expf(ms[j] - mnew);
      ms[j] = mnew;
      float p0 = __expf(s[0][j] - mnew);
      float p1 = __expf(s[1][j] - mnew);
      float p2 = __expf(s[2][j] - mnew);
      float p3 = __expf(s[3][j] - mnew);
      float ps = p0 + p1 + p2 + p3;
      ps += __shfl_xor(ps, 1, 64);
      ps += __shfl_xor(ps, 2, 64);
      ps += __shfl_xor(ps, 4, 64);
      ps += __shfl_xor(ps, 8, 64);
      ls[j] = ls[j] * corr + ps;
      int prow = l4 * 4 + j;
      pl[w][prow][0 * 16 + l15] = f2bf(p0);
      pl[w][prow][1 * 16 + l15] = f2bf(p1);
      pl[w][prow][2 * 16 + l15] = f2bf(p2);
      pl[w][prow][3 * 16 + l15] = f2bf(p3);
#pragma unroll
      for (int dn = 0; dn < 8; ++dn) acc[dn][j] *= corr;
    }

    __builtin_amdgcn_s_setprio(1);
#pragma unroll
    for (int kc = 0; kc < 2; ++kc) {
      bf16w8 pa = *(const bf16w8*)&pl[w][l15][kc * 32 + l4 * 8];
      const unsigned short* vr = Vbase + kbase + kc * 32;
#pragma unroll
      for (int dn = 0; dn < 8; ++dn)
        acc[dn] = __builtin_amdgcn_mfma_f32_16x16x32_bf16(
            pa, *(const bf16w8*)(vr + (size_t)dn * 16 * T_SEQ), acc[dn], 0, 0, 0);
    }
    __builtin_amdgcn_s_setprio(0);
  }

  float inv[4];
#pragma unroll
  for (int j = 0; j < 4; ++j) inv[j] = 1.0f / ls[j];
#pragma unroll
  for (int dn = 0; dn < 8; ++dn)
#pragma unroll
    for (int j = 0; j < 4; ++j) {
      int qrow2 = q0 + w * 16 + l4 * 4 + j;
      Ob[(size_t)(b * T_SEQ + qrow2) * C_DIM + h * HD + dn * 16 + l15] =
          f2bf(acc[dn][j] * inv[j]);
    }
}

// ---------------------------------------------------------------------------
// Launch
// ---------------------------------------------------------------------------
extern "C" void kernel_launch(void* const* d_in, const int* in_sizes, int n_in,
                              void* d_out, int out_size, void* d_ws, size_t ws_size,
                              hipStream_t stream) {
  const float* x  = (const float*)d_in[0];
  const float* wq = (const float*)d_in[1];
  const float* wk = (const float*)d_in[2];
  const float* wv = (const float*)d_in[3];
  const float* wo = (const float*)d_in[4];
  const float* qw = (const float*)d_in[5];
  const float* kw = (const float*)d_in[6];
  float* out = (float*)d_out;

  char* p = (char*)d_ws;
  auto alloc = [&](size_t bytes) { void* r = (void*)p; p += (bytes + 255) & ~(size_t)255; return r; };
  float* qp   = (float*)alloc((size_t)M_ROWS * C_DIM * 4);
  float* kp   = (float*)alloc((size_t)M_ROWS * KV_DIM * 4);
  float* vp   = (float*)alloc((size_t)M_ROWS * KV_DIM * 4);
  float* cost = (float*)alloc((size_t)T_SEQ * 64 * 4);
  float* sint = (float*)alloc((size_t)T_SEQ * 64 * 4);
  unsigned short* xb   = (unsigned short*)alloc((size_t)M_ROWS * C_DIM * 2);
  unsigned short* wqb  = (unsigned short*)alloc((size_t)C_DIM * C_DIM * 2);
  unsigned short* wkb  = (unsigned short*)alloc((size_t)KV_DIM * C_DIM * 2);
  unsigned short* wvb  = (unsigned short*)alloc((size_t)KV_DIM * C_DIM * 2);
  unsigned short* wob  = (unsigned short*)alloc((size_t)C_DIM * C_DIM * 2);
  unsigned short* qb   = (unsigned short*)alloc((size_t)M_ROWS * C_DIM * 2);
  unsigned short* kb   = (unsigned short*)alloc((size_t)M_ROWS * KV_DIM * 2);
  unsigned short* vt   = (unsigned short*)alloc((size_t)M_ROWS * KV_DIM * 2);
  unsigned short* attb = (unsigned short*)alloc((size_t)M_ROWS * C_DIM * 2);

  dim3 blk(256);
  rope_tables<<<dim3(T_SEQ), dim3(64), 0, stream>>>(cost, sint);

  // bf16 conversions
  cvt_f32_bf16<<<dim3(M_ROWS * C_DIM / 2048), blk, 0, stream>>>(x, xb, M_ROWS * C_DIM / 8);
  cvt_f32_bf16<<<dim3(C_DIM * C_DIM / 2048), blk, 0, stream>>>(wq, wqb, C_DIM * C_DIM / 8);
  cvt_f32_bf16<<<dim3(KV_DIM * C_DIM / 2048), blk, 0, stream>>>(wk, wkb, KV_DIM * C_DIM / 8);
  cvt_f32_bf16<<<dim3(KV_DIM * C_DIM / 2048), blk, 0, stream>>>(wv, wvb, KV_DIM * C_DIM / 8);
  cvt_f32_bf16<<<dim3(C_DIM * C_DIM / 2048), blk, 0, stream>>>(wo, wob, C_DIM * C_DIM / 8);

  // Projections (bf16 MFMA, fp32 out)
  gemm_bt_bf16<<<dim3(C_DIM / 128, M_ROWS / 128), blk, 0, stream>>>(
      xb, wqb, qp, M_ROWS, C_DIM, C_DIM);
  gemm_bt_bf16<<<dim3(KV_DIM / 128, M_ROWS / 128), blk, 0, stream>>>(
      xb, wkb, kp, M_ROWS, KV_DIM, C_DIM);
  gemm_bt_bf16<<<dim3(KV_DIM / 128, M_ROWS / 128), blk, 0, stream>>>(
      xb, wvb, vp, M_ROWS, KV_DIM, C_DIM);

  // RMSNorm + RoPE -> bf16 (fold 1/sqrt(HD) into Q)
  norm_rope_bf16<<<dim3(M_ROWS * NH / 4), blk, 0, stream>>>(
      qp, qb, qw, cost, sint, NH, 0.08838834764831845f);
  norm_rope_bf16<<<dim3(M_ROWS * NKV / 4), blk, 0, stream>>>(
      kp, kb, kw, cost, sint, NKV, 1.0f);

  // V -> transposed bf16
  transpose_v<<<dim3(M_ROWS / 64, KV_DIM / 64), blk, 0, stream>>>(vp, vt);

  // Flash attention
  attn_mfma<<<dim3(NB * NH * (T_SEQ / 64)), blk, 0, stream>>>(qb, kb, vt, attb);

  // Output projection
  gemm_bt_bf16<<<dim3(C_DIM / 128, M_ROWS / 128), blk, 0, stream>>>(
      attb, wob, out, M_ROWS, C_DIM, C_DIM);
}

// Round 3
// 351.124 us; speedup vs baseline: 18.0980x; 2.1447x over previous
//
#include <hip/hip_runtime.h>
#include <math.h>

// Problem constants (B=2, T=2048, C=2048, 16 heads, 4 KV heads, HD=128)
#define NB 2
#define T_SEQ 2048
#define C_DIM 2048
#define NH 16
#define NKV 4
#define HD 128
#define KV_DIM (NKV * HD)   // 512
#define M_ROWS (NB * T_SEQ) // 4096

typedef short bf16w8 __attribute__((ext_vector_type(8)));   // MFMA A/B frag (8 bf16)
typedef float f32x4 __attribute__((ext_vector_type(4)));    // 16x16 C/D frag
typedef float f32x16 __attribute__((ext_vector_type(16)));  // 32x32 C/D frag
typedef unsigned short u16x8 __attribute__((ext_vector_type(8)));
typedef unsigned short u16x4 __attribute__((ext_vector_type(4)));

__device__ __forceinline__ unsigned short f2bf(float x) {
  union { float f; unsigned u; } v; v.f = x;
  return (unsigned short)((v.u + 0x7FFFu + ((v.u >> 16) & 1u)) >> 16);
}

// packed bf16 pair: low = lo, high = hi
__device__ __forceinline__ unsigned int cvt_pk_bf16(float lo, float hi) {
  unsigned int r;
  asm("v_cvt_pk_bf16_f32 %0, %1, %2" : "=v"(r) : "v"(lo), "v"(hi));
  return r;
}

__device__ __forceinline__ float wave_reduce_sum(float v) {
#pragma unroll
  for (int off = 32; off > 0; off >>= 1) v += __shfl_xor(v, off, 64);
  return v;
}

// ---------------------------------------------------------------------------
// fp32 -> bf16 bulk convert (16B stores). n8 = elems/8, sizes divisible by 8.
// ---------------------------------------------------------------------------
__global__ __launch_bounds__(256) void cvt_f32_bf16(
    const float* __restrict__ in, unsigned short* __restrict__ out, int n8) {
  int i = blockIdx.x * 256 + threadIdx.x;
  if (i >= n8) return;
  float4 a = ((const float4*)in)[i * 2];
  float4 b = ((const float4*)in)[i * 2 + 1];
  u16x8 o;
  o[0] = f2bf(a.x); o[1] = f2bf(a.y); o[2] = f2bf(a.z); o[3] = f2bf(a.w);
  o[4] = f2bf(b.x); o[5] = f2bf(b.y); o[6] = f2bf(b.z); o[7] = f2bf(b.w);
  *(u16x8*)(out + (size_t)i * 8) = o;
}

// ---------------------------------------------------------------------------
// RoPE cos/sin tables: [T][64] each. theta = 500000.
// ---------------------------------------------------------------------------
__global__ void rope_tables(float* __restrict__ cost, float* __restrict__ sint) {
  int t = blockIdx.x;
  int i = threadIdx.x; // 0..63
  float inv_freq = powf(500000.0f, -(float)i / 64.0f);
  float ang = (float)t * inv_freq;
  cost[t * 64 + i] = cosf(ang);
  sint[t * 64 + i] = sinf(ang);
}

// ---------------------------------------------------------------------------
// GEMM: C[M][N] = A[M][K] * W[N][K]^T, A/W bf16 (ushort), C fp32.
// 128x128 tile, BK=64, 4 waves (2x2), per-wave 64x64 via 4x4 mfma 16x16x32.
// LDS XOR-swizzled (granule ^ (row&7)) -> conflict-free ds_read_b128 (T2).
// ---------------------------------------------------------------------------
__global__ __launch_bounds__(256) void gemm_bt_bf16(
    const unsigned short* __restrict__ A, const unsigned short* __restrict__ W,
    float* __restrict__ C, int M, int N, int K) {
  __shared__ __align__(16) unsigned short As[128][64];
  __shared__ __align__(16) unsigned short Ws[128][64];
  int tid = threadIdx.x;
  int lane = tid & 63;
  int wid = tid >> 6;
  int wr = wid >> 1, wc = wid & 1;
  int l15 = lane & 15, l4 = lane >> 4;
  int bx = blockIdx.x, by = blockIdx.y;

  int lrow = tid >> 1;          // 0..127
  int lg0 = (tid & 1) * 4;      // granule base (8 bf16 per granule)
  int swz = lrow & 7;

  const unsigned short* Abase = A + (size_t)(by * 128 + lrow) * K + lg0 * 8;
  const unsigned short* Wbase = W + (size_t)(bx * 128 + lrow) * K + lg0 * 8;

  f32x4 zero = {0.f, 0.f, 0.f, 0.f};
  f32x4 acc[4][4];
#pragma unroll
  for (int m = 0; m < 4; ++m)
#pragma unroll
    for (int n = 0; n < 4; ++n) acc[m][n] = zero;

  for (int k0 = 0; k0 < K; k0 += 64) {
    u16x8 av[4], wv[4];
#pragma unroll
    for (int i = 0; i < 4; ++i) {
      av[i] = *(const u16x8*)(Abase + k0 + i * 8);
      wv[i] = *(const u16x8*)(Wbase + k0 + i * 8);
    }
    __syncthreads();
#pragma unroll
    for (int i = 0; i < 4; ++i) {
      int g = lg0 + i;
      *(u16x8*)&As[lrow][(g ^ swz) * 8] = av[i];
      *(u16x8*)&Ws[lrow][(g ^ swz) * 8] = wv[i];
    }
    __syncthreads();

    bf16w8 af[2][4], bw[2][4];
#pragma unroll
    for (int kk = 0; kk < 2; ++kk) {
#pragma unroll
      for (int m = 0; m < 4; ++m) {
        int r = wr * 64 + m * 16 + l15;
        int g = (kk * 4 + l4) ^ (r & 7);
        af[kk][m] = *(const bf16w8*)&As[r][g * 8];
      }
#pragma unroll
      for (int n = 0; n < 4; ++n) {
        int r = wc * 64 + n * 16 + l15;
        int g = (kk * 4 + l4) ^ (r & 7);
        bw[kk][n] = *(const bf16w8*)&Ws[r][g * 8];
      }
    }
#pragma unroll
    for (int kk = 0; kk < 2; ++kk)
#pragma unroll
      for (int m = 0; m < 4; ++m)
#pragma unroll
        for (int n = 0; n < 4; ++n)
          acc[m][n] = __builtin_amdgcn_mfma_f32_16x16x32_bf16(
              af[kk][m], bw[kk][n], acc[m][n], 0, 0, 0);
  }

#pragma unroll
  for (int m = 0; m < 4; ++m)
#pragma unroll
    for (int n = 0; n < 4; ++n)
#pragma unroll
      for (int j = 0; j < 4; ++j) {
        int row = by * 128 + wr * 64 + m * 16 + l4 * 4 + j;
        int col = bx * 128 + wc * 64 + n * 16 + l15;
        C[(size_t)row * N + col] = acc[m][n][j];
      }
}

// ---------------------------------------------------------------------------
// Per-head RMSNorm + RoPE, fp32 in -> bf16 out (scale folded for Q).
// One wave per (bt, head) row; lane l owns dims l and l+64.
// ---------------------------------------------------------------------------
__global__ __launch_bounds__(256) void norm_rope_bf16(
    const float* __restrict__ X, unsigned short* __restrict__ Y,
    const float* __restrict__ w, const float* __restrict__ cost,
    const float* __restrict__ sint, int nheads, float oscale) {
  int wid = (blockIdx.x * 256 + threadIdx.x) >> 6;
  int lane = threadIdx.x & 63;
  int h = wid % nheads;
  int bt = wid / nheads;
  int t = bt & (T_SEQ - 1);
  const float* row = X + (size_t)bt * (nheads * HD) + h * HD;
  float x1 = row[lane];
  float x2 = row[lane + 64];
  float ss = wave_reduce_sum(x1 * x1 + x2 * x2);
  float r = rsqrtf(ss * (1.0f / 128.0f) + 1e-6f);
  x1 = x1 * r * w[lane];
  x2 = x2 * r * w[lane + 64];
  float c = cost[t * 64 + lane];
  float s = sint[t * 64 + lane];
  unsigned short* yrow = Y + (size_t)bt * (nheads * HD) + h * HD;
  yrow[lane]      = f2bf((x1 * c - x2 * s) * oscale);
  yrow[lane + 64] = f2bf((x2 * c + x1 * s) * oscale);
}

// ---------------------------------------------------------------------------
// V transpose: vp fp32 [B*T][512] -> vt bf16 [(b*512 + c)][T]  (c = kvh*128+d)
// ---------------------------------------------------------------------------
__global__ __launch_bounds__(256) void transpose_v(
    const float* __restrict__ Vp, unsigned short* __restrict__ Vt) {
  __shared__ float tile[64][65];
  int bt_tile = blockIdx.x;           // 0..63  (b*32 + ttile)
  int ct = blockIdx.y;                // 0..7
  int b = bt_tile >> 5;
  int t0 = (bt_tile & 31) * 64;
  int c0 = ct * 64;
  int tid = threadIdx.x;
  int r = tid >> 4;                   // 0..15
  int c4 = (tid & 15) * 4;
#pragma unroll
  for (int p = 0; p < 4; ++p) {
    int row = r + p * 16;
    float4 v = *(const float4*)&Vp[(size_t)(b * T_SEQ + t0 + row) * KV_DIM + c0 + c4];
    tile[row][c4] = v.x; tile[row][c4 + 1] = v.y;
    tile[row][c4 + 2] = v.z; tile[row][c4 + 3] = v.w;
  }
  __syncthreads();
#pragma unroll
  for (int p = 0; p < 4; ++p) {
    int drow = r + p * 16;            // local col index = output row
    int cg = c0 + drow;
    u16x4 o;
    o[0] = f2bf(tile[c4 + 0][drow]);
    o[1] = f2bf(tile[c4 + 1][drow]);
    o[2] = f2bf(tile[c4 + 2][drow]);
    o[3] = f2bf(tile[c4 + 3][drow]);
    *(u16x4*)&Vt[(size_t)(b * KV_DIM + cg) * T_SEQ + t0 + c4] = o;
  }
}

// ---------------------------------------------------------------------------
// Causal GQA flash attention v3: swapped-operand 32x32x16 MFMA, in-register
// softmax (q lane-local), no LDS, defer-max, exp2 domain.
// Qb [B*T][2048] bf16 pre-scaled by log2(e)/sqrt(128); Kb [B*T][512] bf16;
// Vt [(b*512+c)][T] bf16 (V^T); Ob [B*T][2048] bf16.
// One wave = 32 q-rows of one head. 4 waves/block, mirror-paired q-tiles for
// uniform block work; XCD swizzle keeps same-(b,kvh) blocks on one L2.
// S^T = mfma(A=K, B=Q): col=q=lane&31, row=key=(reg&3)+8*(reg>>2)+4*(lane>>5).
// O^T = mfma(A=V^T, B=P^T): P^T B-frags assembled via cvt_pk + shfl_xor(32).
// ---------------------------------------------------------------------------
__global__ __launch_bounds__(256, 2) void attn_mfma2(
    const unsigned short* __restrict__ Qb, const unsigned short* __restrict__ Kb,
    const unsigned short* __restrict__ Vt, unsigned short* __restrict__ Ob) {
  int lane = threadIdx.x & 63;
  int q31 = lane & 31;
  int hi = lane >> 5;

  int bid = blockIdx.x;
  int swz = (bid & 7) * 64 + (bid >> 3);       // XCD-contiguous remap (512 % 8 == 0)
  int task = swz * 4 + (threadIdx.x >> 6);
  int side = task & 1;
  int pr = task >> 1;                          // 0..1023
  int jj = pr & 31;
  int h = (pr >> 5) & 15;
  int b = pr >> 9;
  int qtile = side ? (63 - jj) : jj;           // mirror pairing: uniform work
  int q0 = qtile * 32;
  int kvh = h >> 2;

  // Q fragments (B-operand): col=q=q31, k = kc*16 + hi*8 + j
  const unsigned short* qptr =
      Qb + ((size_t)(b * T_SEQ + q0 + q31)) * C_DIM + h * HD + hi * 8;
  bf16w8 qf[8];
#pragma unroll
  for (int kc = 0; kc < 8; ++kc) qf[kc] = *(const bf16w8*)(qptr + kc * 16);

  const unsigned short* kptr =
      Kb + ((size_t)(b * T_SEQ)) * KV_DIM + kvh * HD + hi * 8;
  const unsigned short* vptr =
      Vt + ((size_t)(b * KV_DIM + kvh * HD + q31)) * T_SEQ + hi * 8;

  f32x16 acc[4];
#pragma unroll
  for (int dt = 0; dt < 4; ++dt)
#pragma unroll
    for (int r = 0; r < 16; ++r) acc[dt][r] = 0.f;
  float m = -INFINITY, l = 0.f;

  int ktend = qtile;
  for (int kt = 0; kt <= ktend; ++kt) {
    // K fragments (A-operand): row=key_local=q31, k = kc*16 + hi*8 + j
    const unsigned short* krow = kptr + (size_t)(kt * 32 + q31) * KV_DIM;
    bf16w8 kf[8];
#pragma unroll
    for (int kc = 0; kc < 8; ++kc) kf[kc] = *(const bf16w8*)(krow + kc * 16);

    f32x16 s;
#pragma unroll
    for (int r = 0; r < 16; ++r) s[r] = 0.f;
    __builtin_amdgcn_s_setprio(1);
#pragma unroll
    for (int kc = 0; kc < 8; ++kc)
      s = __builtin_amdgcn_mfma_f32_32x32x16_bf16(kf[kc], qf[kc], s, 0, 0, 0);
    __builtin_amdgcn_s_setprio(0);

    // V^T fragments for this key block (independent of softmax -> overlap)
    bf16w8 vf[8];
#pragma unroll
    for (int dt = 0; dt < 4; ++dt)
#pragma unroll
      for (int kc = 0; kc < 2; ++kc)
        vf[dt * 2 + kc] = *(const bf16w8*)(vptr + (size_t)dt * 32 * T_SEQ +
                                           kt * 32 + kc * 16);

    if (kt == ktend) {  // diagonal: mask key > q
#pragma unroll
      for (int r = 0; r < 16; ++r) {
        int key = (r & 3) + 8 * (r >> 2) + 4 * hi;  // + kt*32, vs q = q0 + q31
        if (kt * 32 + key > q0 + q31) s[r] = -INFINITY;
      }
    }

    float tmax = s[0];
#pragma unroll
    for (int r = 1; r < 16; ++r) tmax = fmaxf(tmax, s[r]);
    tmax = fmaxf(tmax, __shfl_xor(tmax, 32, 64));

    if (!__all(tmax <= m + 8.0f)) {   // defer-max (T13)
      float mnew = fmaxf(m, tmax);
      float corr = exp2f(m - mnew);
      l *= corr;
#pragma unroll
      for (int dt = 0; dt < 4; ++dt)
#pragma unroll
        for (int r = 0; r < 16; ++r) acc[dt][r] *= corr;
      m = mnew;
    }

    float p[16];
    float ps = 0.f;
#pragma unroll
    for (int r = 0; r < 16; ++r) {
      p[r] = exp2f(s[r] - m);
      ps += p[r];
    }
    ps += __shfl_xor(ps, 32, 64);
    l += ps;

    unsigned int w[8];
#pragma unroll
    for (int r = 0; r < 8; ++r) w[r] = cvt_pk_bf16(p[2 * r], p[2 * r + 1]);

    __builtin_amdgcn_s_setprio(1);
#pragma unroll
    for (int kc = 0; kc < 2; ++kc) {
      // exchange: hi=0 sends w[4kc+2],w[4kc+3]; hi=1 sends w[4kc],w[4kc+1]
      unsigned int s0 = hi ? w[4 * kc] : w[4 * kc + 2];
      unsigned int s1 = hi ? w[4 * kc + 1] : w[4 * kc + 3];
      unsigned int z0 = (unsigned int)__shfl_xor((int)s0, 32, 64);
      unsigned int z1 = (unsigned int)__shfl_xor((int)s1, 32, 64);
      union { unsigned int u[4]; bf16w8 v; } pf;
      pf.u[0] = hi ? z0 : w[4 * kc];
      pf.u[1] = hi ? z1 : w[4 * kc + 1];
      pf.u[2] = hi ? w[4 * kc + 2] : z0;
      pf.u[3] = hi ? w[4 * kc + 3] : z1;
#pragma unroll
      for (int dt = 0; dt < 4; ++dt)
        acc[dt] = __builtin_amdgcn_mfma_f32_32x32x16_bf16(
            vf[dt * 2 + kc], pf.v, acc[dt], 0, 0, 0);
    }
    __builtin_amdgcn_s_setprio(0);
  }

  float inv = 1.0f / l;
  // O^T: lane q = q31 fixed; d = dt*32 + 8*(r>>2) + 4*hi + (r&3)
  unsigned short* orow =
      Ob + ((size_t)(b * T_SEQ + q0 + q31)) * C_DIM + h * HD + hi * 4;
#pragma unroll
  for (int dt = 0; dt < 4; ++dt)
#pragma unroll
    for (int rq = 0; rq < 4; ++rq) {
      unsigned int w0 = cvt_pk_bf16(acc[dt][rq * 4 + 0] * inv, acc[dt][rq * 4 + 1] * inv);
      unsigned int w1 = cvt_pk_bf16(acc[dt][rq * 4 + 2] * inv, acc[dt][rq * 4 + 3] * inv);
      uint2 st; st.x = w0; st.y = w1;
      *(uint2*)(orow + dt * 32 + rq * 8) = st;
    }
}

// ---------------------------------------------------------------------------
// Launch
// ---------------------------------------------------------------------------
extern "C" void kernel_launch(void* const* d_in, const int* in_sizes, int n_in,
                              void* d_out, int out_size, void* d_ws, size_t ws_size,
                              hipStream_t stream) {
  const float* x  = (const float*)d_in[0];
  const float* wq = (const float*)d_in[1];
  const float* wk = (const float*)d_in[2];
  const float* wv = (const float*)d_in[3];
  const float* wo = (const float*)d_in[4];
  const float* qw = (const float*)d_in[5];
  const float* kw = (const float*)d_in[6];
  float* out = (float*)d_out;

  char* p = (char*)d_ws;
  auto alloc = [&](size_t bytes) { void* r = (void*)p; p += (bytes + 255) & ~(size_t)255; return r; };
  float* qp   = (float*)alloc((size_t)M_ROWS * C_DIM * 4);
  float* kp   = (float*)alloc((size_t)M_ROWS * KV_DIM * 4);
  float* vp   = (float*)alloc((size_t)M_ROWS * KV_DIM * 4);
  float* cost = (float*)alloc((size_t)T_SEQ * 64 * 4);
  float* sint = (float*)alloc((size_t)T_SEQ * 64 * 4);
  unsigned short* xb   = (unsigned short*)alloc((size_t)M_ROWS * C_DIM * 2);
  unsigned short* wqb  = (unsigned short*)alloc((size_t)C_DIM * C_DIM * 2);
  unsigned short* wkb  = (unsigned short*)alloc((size_t)KV_DIM * C_DIM * 2);
  unsigned short* wvb  = (unsigned short*)alloc((size_t)KV_DIM * C_DIM * 2);
  unsigned short* wob  = (unsigned short*)alloc((size_t)C_DIM * C_DIM * 2);
  unsigned short* qb   = (unsigned short*)alloc((size_t)M_ROWS * C_DIM * 2);
  unsigned short* kb   = (unsigned short*)alloc((size_t)M_ROWS * KV_DIM * 2);
  unsigned short* vt   = (unsigned short*)alloc((size_t)M_ROWS * KV_DIM * 2);
  unsigned short* attb = (unsigned short*)alloc((size_t)M_ROWS * C_DIM * 2);

  dim3 blk(256);
  rope_tables<<<dim3(T_SEQ), dim3(64), 0, stream>>>(cost, sint);

  // bf16 conversions
  cvt_f32_bf16<<<dim3(M_ROWS * C_DIM / 2048), blk, 0, stream>>>(x, xb, M_ROWS * C_DIM / 8);
  cvt_f32_bf16<<<dim3(C_DIM * C_DIM / 2048), blk, 0, stream>>>(wq, wqb, C_DIM * C_DIM / 8);
  cvt_f32_bf16<<<dim3(KV_DIM * C_DIM / 2048), blk, 0, stream>>>(wk, wkb, KV_DIM * C_DIM / 8);
  cvt_f32_bf16<<<dim3(KV_DIM * C_DIM / 2048), blk, 0, stream>>>(wv, wvb, KV_DIM * C_DIM / 8);
  cvt_f32_bf16<<<dim3(C_DIM * C_DIM / 2048), blk, 0, stream>>>(wo, wob, C_DIM * C_DIM / 8);

  // Projections (bf16 MFMA, fp32 out)
  gemm_bt_bf16<<<dim3(C_DIM / 128, M_ROWS / 128), blk, 0, stream>>>(
      xb, wqb, qp, M_ROWS, C_DIM, C_DIM);
  gemm_bt_bf16<<<dim3(KV_DIM / 128, M_ROWS / 128), blk, 0, stream>>>(
      xb, wkb, kp, M_ROWS, KV_DIM, C_DIM);
  gemm_bt_bf16<<<dim3(KV_DIM / 128, M_ROWS / 128), blk, 0, stream>>>(
      xb, wvb, vp, M_ROWS, KV_DIM, C_DIM);

  // RMSNorm + RoPE -> bf16. Q scale folds 1/sqrt(HD) AND log2(e) (exp2 domain).
  const float qscale = 0.08838834764831845f * 1.4426950408889634f;
  norm_rope_bf16<<<dim3(M_ROWS * NH / 4), blk, 0, stream>>>(
      qp, qb, qw, cost, sint, NH, qscale);
  norm_rope_bf16<<<dim3(M_ROWS * NKV / 4), blk, 0, stream>>>(
      kp, kb, kw, cost, sint, NKV, 1.0f);

  // V -> transposed bf16 (V^T)
  transpose_v<<<dim3(M_ROWS / 64, KV_DIM / 64), blk, 0, stream>>>(vp, vt);

  // Flash attention v3: 2048 wave-tasks, 4/block, mirror-paired
  attn_mfma2<<<dim3(512), blk, 0, stream>>>(qb, kb, vt, attb);

  // Output projection
  gemm_bt_bf16<<<dim3(C_DIM / 128, M_ROWS / 128), blk, 0, stream>>>(
      attb, wob, out, M_ROWS, C_DIM, C_DIM);
}

// Round 4
// 315.109 us; speedup vs baseline: 20.1664x; 1.1143x over previous
//
#include <hip/hip_runtime.h>
#include <math.h>

// Problem constants (B=2, T=2048, C=2048, 16 heads, 4 KV heads, HD=128)
#define NB 2
#define T_SEQ 2048
#define C_DIM 2048
#define NH 16
#define NKV 4
#define HD 128
#define KV_DIM (NKV * HD)   // 512
#define M_ROWS (NB * T_SEQ) // 4096

typedef short bf16w8 __attribute__((ext_vector_type(8)));   // MFMA A/B frag (8 bf16)
typedef float f32x4 __attribute__((ext_vector_type(4)));    // 16x16 C/D frag
typedef float f32x16 __attribute__((ext_vector_type(16)));  // 32x32 C/D frag
typedef unsigned short u16x8 __attribute__((ext_vector_type(8)));
typedef unsigned short u16x4 __attribute__((ext_vector_type(4)));

__device__ __forceinline__ unsigned short f2bf(float x) {
  union { float f; unsigned u; } v; v.f = x;
  return (unsigned short)((v.u + 0x7FFFu + ((v.u >> 16) & 1u)) >> 16);
}

// packed bf16 pair: low = lo, high = hi
__device__ __forceinline__ unsigned int cvt_pk_bf16(float lo, float hi) {
  unsigned int r;
  asm("v_cvt_pk_bf16_f32 %0, %1, %2" : "=v"(r) : "v"(lo), "v"(hi));
  return r;
}

__device__ __forceinline__ float wave_reduce_sum(float v) {
#pragma unroll
  for (int off = 32; off > 0; off >>= 1) v += __shfl_xor(v, off, 64);
  return v;
}

// ---------------------------------------------------------------------------
// fp32 -> bf16 bulk convert (16B stores). n8 = elems/8, sizes divisible by 8.
// ---------------------------------------------------------------------------
__global__ __launch_bounds__(256) void cvt_f32_bf16(
    const float* __restrict__ in, unsigned short* __restrict__ out, int n8) {
  int i = blockIdx.x * 256 + threadIdx.x;
  if (i >= n8) return;
  float4 a = ((const float4*)in)[i * 2];
  float4 b = ((const float4*)in)[i * 2 + 1];
  u16x8 o;
  o[0] = f2bf(a.x); o[1] = f2bf(a.y); o[2] = f2bf(a.z); o[3] = f2bf(a.w);
  o[4] = f2bf(b.x); o[5] = f2bf(b.y); o[6] = f2bf(b.z); o[7] = f2bf(b.w);
  *(u16x8*)(out + (size_t)i * 8) = o;
}

// ---------------------------------------------------------------------------
// RoPE cos/sin tables: [T][64] each. theta = 500000.
// ---------------------------------------------------------------------------
__global__ void rope_tables(float* __restrict__ cost, float* __restrict__ sint) {
  int t = blockIdx.x;
  int i = threadIdx.x; // 0..63
  float inv_freq = powf(500000.0f, -(float)i / 64.0f);
  float ang = (float)t * inv_freq;
  cost[t * 64 + i] = cosf(ang);
  sint[t * 64 + i] = sinf(ang);
}

// ---------------------------------------------------------------------------
// GEMM (m97 structure): C[M][N] = A[M][K] * W[N][K]^T, A/W bf16, C fp32.
// 128x128 tile, BK=64, 4 waves (2x2), 4x4 mfma_16x16x32 per wave.
// Staging via global_load_lds width=16 into LINEAR LDS [128][64]
// (wave-uniform LDS base + lane*16B; per-lane global source).
// 2 barriers per K-step (m97's proven 874-TF structure at 128^2).
// ---------------------------------------------------------------------------
__global__ __launch_bounds__(256) void gemm_lds_bf16(
    const unsigned short* __restrict__ A, const unsigned short* __restrict__ W,
    float* __restrict__ C, int M, int N, int K) {
  __shared__ __align__(16) unsigned short As[128 * 64];
  __shared__ __align__(16) unsigned short Ws[128 * 64];
  int tid = threadIdx.x;
  int lane = tid & 63;
  int w = tid >> 6;
  int wr = w >> 1, wc = w & 1;
  int l15 = lane & 15, l4 = lane >> 4;

  // Staging map: segment = 8 rows x 64 k (1024B). Wave w owns segments
  // w*4+i (i<4) of each tile. Lane: row = lane>>3, kcol = (lane&7)*8.
  int segrow = lane >> 3;
  int segk = (lane & 7) * 8;
  const unsigned short* Ag =
      A + (size_t)(blockIdx.y * 128 + w * 32 + segrow) * K + segk;
  const unsigned short* Wg =
      W + (size_t)(blockIdx.x * 128 + w * 32 + segrow) * K + segk;

  f32x4 zero = {0.f, 0.f, 0.f, 0.f};
  f32x4 acc[4][4];
#pragma unroll
  for (int m = 0; m < 4; ++m)
#pragma unroll
    for (int n = 0; n < 4; ++n) acc[m][n] = zero;

  for (int k0 = 0; k0 < K; k0 += 64) {
    __syncthreads();  // previous iteration's LDS reads complete
#pragma unroll
    for (int i = 0; i < 4; ++i) {
      __builtin_amdgcn_global_load_lds(
          (const __attribute__((address_space(1))) void*)(Ag + k0 + (size_t)i * 8 * K),
          (__attribute__((address_space(3))) void*)&As[(w * 32 + i * 8) * 64],
          16, 0, 0);
      __builtin_amdgcn_global_load_lds(
          (const __attribute__((address_space(1))) void*)(Wg + k0 + (size_t)i * 8 * K),
          (__attribute__((address_space(3))) void*)&Ws[(w * 32 + i * 8) * 64],
          16, 0, 0);
    }
    __syncthreads();  // compiler drains vmcnt(0) before barrier

    bf16w8 af[2][4], bw[2][4];
#pragma unroll
    for (int kk = 0; kk < 2; ++kk) {
#pragma unroll
      for (int m = 0; m < 4; ++m)
        af[kk][m] = *(const bf16w8*)&As[(wr * 64 + m * 16 + l15) * 64 + kk * 32 + l4 * 8];
#pragma unroll
      for (int n = 0; n < 4; ++n)
        bw[kk][n] = *(const bf16w8*)&Ws[(wc * 64 + n * 16 + l15) * 64 + kk * 32 + l4 * 8];
    }
#pragma unroll
    for (int kk = 0; kk < 2; ++kk)
#pragma unroll
      for (int m = 0; m < 4; ++m)
#pragma unroll
        for (int n = 0; n < 4; ++n)
          acc[m][n] = __builtin_amdgcn_mfma_f32_16x16x32_bf16(
              af[kk][m], bw[kk][n], acc[m][n], 0, 0, 0);
  }

#pragma unroll
  for (int m = 0; m < 4; ++m)
#pragma unroll
    for (int n = 0; n < 4; ++n)
#pragma unroll
      for (int j = 0; j < 4; ++j) {
        int row = blockIdx.y * 128 + wr * 64 + m * 16 + l4 * 4 + j;
        int col = blockIdx.x * 128 + wc * 64 + n * 16 + l15;
        C[(size_t)row * N + col] = acc[m][n][j];
      }
}

// ---------------------------------------------------------------------------
// Per-head RMSNorm + RoPE, fp32 in -> bf16 out (scale folded for Q).
// One wave per (bt, head) row; lane l owns dims l and l+64.
// istride/ostride in elements (supports fused-KV layouts).
// ---------------------------------------------------------------------------
__global__ __launch_bounds__(256) void norm_rope_bf16(
    const float* __restrict__ X, unsigned short* __restrict__ Y,
    const float* __restrict__ w, const float* __restrict__ cost,
    const float* __restrict__ sint, int nheads, int istride, int ostride,
    float oscale) {
  int wid = (blockIdx.x * 256 + threadIdx.x) >> 6;
  int lane = threadIdx.x & 63;
  int h = wid % nheads;
  int bt = wid / nheads;
  int t = bt & (T_SEQ - 1);
  const float* row = X + (size_t)bt * istride + h * HD;
  float x1 = row[lane];
  float x2 = row[lane + 64];
  float ss = wave_reduce_sum(x1 * x1 + x2 * x2);
  float r = rsqrtf(ss * (1.0f / 128.0f) + 1e-6f);
  x1 = x1 * r * w[lane];
  x2 = x2 * r * w[lane + 64];
  float c = cost[t * 64 + lane];
  float s = sint[t * 64 + lane];
  unsigned short* yrow = Y + (size_t)bt * ostride + h * HD;
  yrow[lane]      = f2bf((x1 * c - x2 * s) * oscale);
  yrow[lane + 64] = f2bf((x2 * c + x1 * s) * oscale);
}

// ---------------------------------------------------------------------------
// V transpose: Vp fp32 rows [B*T] (row stride istride) -> Vt bf16
// [(b*512 + c)][T]  (c = kvh*128+d). 64x64 tiles through padded LDS.
// ---------------------------------------------------------------------------
__global__ __launch_bounds__(256) void transpose_v(
    const float* __restrict__ Vp, unsigned short* __restrict__ Vt, int istride) {
  __shared__ float tile[64][65];
  int bt_tile = blockIdx.x;           // 0..63  (b*32 + ttile)
  int ct = blockIdx.y;                // 0..7
  int b = bt_tile >> 5;
  int t0 = (bt_tile & 31) * 64;
  int c0 = ct * 64;
  int tid = threadIdx.x;
  int r = tid >> 4;                   // 0..15
  int c4 = (tid & 15) * 4;
#pragma unroll
  for (int p = 0; p < 4; ++p) {
    int row = r + p * 16;
    float4 v = *(const float4*)&Vp[(size_t)(b * T_SEQ + t0 + row) * istride + c0 + c4];
    tile[row][c4] = v.x; tile[row][c4 + 1] = v.y;
    tile[row][c4 + 2] = v.z; tile[row][c4 + 3] = v.w;
  }
  __syncthreads();
#pragma unroll
  for (int p = 0; p < 4; ++p) {
    int drow = r + p * 16;            // local col index = output row
    int cg = c0 + drow;
    u16x4 o;
    o[0] = f2bf(tile[c4 + 0][drow]);
    o[1] = f2bf(tile[c4 + 1][drow]);
    o[2] = f2bf(tile[c4 + 2][drow]);
    o[3] = f2bf(tile[c4 + 3][drow]);
    *(u16x4*)&Vt[(size_t)(b * KV_DIM + cg) * T_SEQ + t0 + c4] = o;
  }
}

// ---------------------------------------------------------------------------
// Causal GQA flash attention: swapped-operand 32x32x16 MFMA, in-register
// softmax (q lane-local), no LDS, defer-max, exp2 domain.
// Qb [B*T][2048] bf16 pre-scaled by log2(e)/sqrt(128); Kb [B*T][512] bf16;
// Vt [(b*512+c)][T] bf16 (V^T); Ob [B*T][2048] bf16.
// One wave = 32 q-rows of one head; mirror-paired q-tiles for uniform work.
// S^T = mfma(A=K, B=Q): col=q=lane&31, row=key=(reg&3)+8*(reg>>2)+4*(lane>>5).
// O^T = mfma(A=V^T, B=P^T): P^T B-frags assembled via cvt_pk + shfl_xor(32).
// ---------------------------------------------------------------------------
__global__ __launch_bounds__(256, 2) void attn_mfma2(
    const unsigned short* __restrict__ Qb, const unsigned short* __restrict__ Kb,
    const unsigned short* __restrict__ Vt, unsigned short* __restrict__ Ob) {
  int lane = threadIdx.x & 63;
  int q31 = lane & 31;
  int hi = lane >> 5;

  int bid = blockIdx.x;
  int swz = (bid & 7) * 64 + (bid >> 3);       // XCD-contiguous remap (512 % 8 == 0)
  int task = swz * 4 + (threadIdx.x >> 6);
  int side = task & 1;
  int pr = task >> 1;                          // 0..1023
  int jj = pr & 31;
  int h = (pr >> 5) & 15;
  int b = pr >> 9;
  int qtile = side ? (63 - jj) : jj;           // mirror pairing: uniform work
  int q0 = qtile * 32;
  int kvh = h >> 2;

  // Q fragments (B-operand): col=q=q31, k = kc*16 + hi*8 + j
  const unsigned short* qptr =
      Qb + ((size_t)(b * T_SEQ + q0 + q31)) * C_DIM + h * HD + hi * 8;
  bf16w8 qf[8];
#pragma unroll
  for (int kc = 0; kc < 8; ++kc) qf[kc] = *(const bf16w8*)(qptr + kc * 16);

  const unsigned short* kptr =
      Kb + ((size_t)(b * T_SEQ)) * KV_DIM + kvh * HD + hi * 8;
  const unsigned short* vptr =
      Vt + ((size_t)(b * KV_DIM + kvh * HD + q31)) * T_SEQ + hi * 8;

  f32x16 acc[4];
#pragma unroll
  for (int dt = 0; dt < 4; ++dt)
#pragma unroll
    for (int r = 0; r < 16; ++r) acc[dt][r] = 0.f;
  float m = -INFINITY, l = 0.f;

  int ktend = qtile;
  for (int kt = 0; kt <= ktend; ++kt) {
    // K fragments (A-operand): row=key_local=q31, k = kc*16 + hi*8 + j
    const unsigned short* krow = kptr + (size_t)(kt * 32 + q31) * KV_DIM;
    bf16w8 kf[8];
#pragma unroll
    for (int kc = 0; kc < 8; ++kc) kf[kc] = *(const bf16w8*)(krow + kc * 16);

    f32x16 s;
#pragma unroll
    for (int r = 0; r < 16; ++r) s[r] = 0.f;
    __builtin_amdgcn_s_setprio(1);
#pragma unroll
    for (int kc = 0; kc < 8; ++kc)
      s = __builtin_amdgcn_mfma_f32_32x32x16_bf16(kf[kc], qf[kc], s, 0, 0, 0);
    __builtin_amdgcn_s_setprio(0);

    // V^T fragments for this key block (independent of softmax -> overlap)
    bf16w8 vf[8];
#pragma unroll
    for (int dt = 0; dt < 4; ++dt)
#pragma unroll
      for (int kc = 0; kc < 2; ++kc)
        vf[dt * 2 + kc] = *(const bf16w8*)(vptr + (size_t)dt * 32 * T_SEQ +
                                           kt * 32 + kc * 16);

    if (kt == ktend) {  // diagonal: mask key > q
#pragma unroll
      for (int r = 0; r < 16; ++r) {
        int key = (r & 3) + 8 * (r >> 2) + 4 * hi;  // + kt*32, vs q = q0 + q31
        if (kt * 32 + key > q0 + q31) s[r] = -INFINITY;
      }
    }

    float tmax = s[0];
#pragma unroll
    for (int r = 1; r < 16; ++r) tmax = fmaxf(tmax, s[r]);
    tmax = fmaxf(tmax, __shfl_xor(tmax, 32, 64));

    if (!__all(tmax <= m + 8.0f)) {   // defer-max (T13)
      float mnew = fmaxf(m, tmax);
      float corr = exp2f(m - mnew);
      l *= corr;
#pragma unroll
      for (int dt = 0; dt < 4; ++dt)
#pragma unroll
        for (int r = 0; r < 16; ++r) acc[dt][r] *= corr;
      m = mnew;
    }

    float p[16];
    float ps = 0.f;
#pragma unroll
    for (int r = 0; r < 16; ++r) {
      p[r] = exp2f(s[r] - m);
      ps += p[r];
    }
    ps += __shfl_xor(ps, 32, 64);
    l += ps;

    unsigned int w[8];
#pragma unroll
    for (int r = 0; r < 8; ++r) w[r] = cvt_pk_bf16(p[2 * r], p[2 * r + 1]);

    __builtin_amdgcn_s_setprio(1);
#pragma unroll
    for (int kc = 0; kc < 2; ++kc) {
      // exchange: hi=0 sends w[4kc+2],w[4kc+3]; hi=1 sends w[4kc],w[4kc+1]
      unsigned int s0 = hi ? w[4 * kc] : w[4 * kc + 2];
      unsigned int s1 = hi ? w[4 * kc + 1] : w[4 * kc + 3];
      unsigned int z0 = (unsigned int)__shfl_xor((int)s0, 32, 64);
      unsigned int z1 = (unsigned int)__shfl_xor((int)s1, 32, 64);
      union { unsigned int u[4]; bf16w8 v; } pf;
      pf.u[0] = hi ? z0 : w[4 * kc];
      pf.u[1] = hi ? z1 : w[4 * kc + 1];
      pf.u[2] = hi ? w[4 * kc + 2] : z0;
      pf.u[3] = hi ? w[4 * kc + 3] : z1;
#pragma unroll
      for (int dt = 0; dt < 4; ++dt)
        acc[dt] = __builtin_amdgcn_mfma_f32_32x32x16_bf16(
            vf[dt * 2 + kc], pf.v, acc[dt], 0, 0, 0);
    }
    __builtin_amdgcn_s_setprio(0);
  }

  float inv = 1.0f / l;
  // O^T: lane q = q31 fixed; d = dt*32 + 8*(r>>2) + 4*hi + (r&3)
  unsigned short* orow =
      Ob + ((size_t)(b * T_SEQ + q0 + q31)) * C_DIM + h * HD + hi * 4;
#pragma unroll
  for (int dt = 0; dt < 4; ++dt)
#pragma unroll
    for (int rq = 0; rq < 4; ++rq) {
      unsigned int w0 = cvt_pk_bf16(acc[dt][rq * 4 + 0] * inv, acc[dt][rq * 4 + 1] * inv);
      unsigned int w1 = cvt_pk_bf16(acc[dt][rq * 4 + 2] * inv, acc[dt][rq * 4 + 3] * inv);
      uint2 st; st.x = w0; st.y = w1;
      *(uint2*)(orow + dt * 32 + rq * 8) = st;
    }
}

// ---------------------------------------------------------------------------
// Launch
// ---------------------------------------------------------------------------
extern "C" void kernel_launch(void* const* d_in, const int* in_sizes, int n_in,
                              void* d_out, int out_size, void* d_ws, size_t ws_size,
                              hipStream_t stream) {
  const float* x  = (const float*)d_in[0];
  const float* wq = (const float*)d_in[1];
  const float* wk = (const float*)d_in[2];
  const float* wv = (const float*)d_in[3];
  const float* wo = (const float*)d_in[4];
  const float* qw = (const float*)d_in[5];
  const float* kw = (const float*)d_in[6];
  float* out = (float*)d_out;

  char* p = (char*)d_ws;
  auto alloc = [&](size_t bytes) { void* r = (void*)p; p += (bytes + 255) & ~(size_t)255; return r; };
  float* qp   = (float*)alloc((size_t)M_ROWS * C_DIM * 4);
  float* kvp  = (float*)alloc((size_t)M_ROWS * 2 * KV_DIM * 4);  // K | V fused
  float* cost = (float*)alloc((size_t)T_SEQ * 64 * 4);
  float* sint = (float*)alloc((size_t)T_SEQ * 64 * 4);
  unsigned short* xb   = (unsigned short*)alloc((size_t)M_ROWS * C_DIM * 2);
  unsigned short* wqb  = (unsigned short*)alloc((size_t)C_DIM * C_DIM * 2);
  unsigned short* wkvb = (unsigned short*)alloc((size_t)2 * KV_DIM * C_DIM * 2);
  unsigned short* wob  = (unsigned short*)alloc((size_t)C_DIM * C_DIM * 2);
  unsigned short* qb   = (unsigned short*)alloc((size_t)M_ROWS * C_DIM * 2);
  unsigned short* kb   = (unsigned short*)alloc((size_t)M_ROWS * KV_DIM * 2);
  unsigned short* vt   = (unsigned short*)alloc((size_t)M_ROWS * KV_DIM * 2);
  unsigned short* attb = (unsigned short*)alloc((size_t)M_ROWS * C_DIM * 2);

  dim3 blk(256);
  rope_tables<<<dim3(T_SEQ), dim3(64), 0, stream>>>(cost, sint);

  // bf16 conversions (wk|wv concatenated -> fused KV weight [1024][2048])
  cvt_f32_bf16<<<dim3(M_ROWS * C_DIM / 2048), blk, 0, stream>>>(x, xb, M_ROWS * C_DIM / 8);
  cvt_f32_bf16<<<dim3(C_DIM * C_DIM / 2048), blk, 0, stream>>>(wq, wqb, C_DIM * C_DIM / 8);
  cvt_f32_bf16<<<dim3(KV_DIM * C_DIM / 2048), blk, 0, stream>>>(wk, wkvb, KV_DIM * C_DIM / 8);
  cvt_f32_bf16<<<dim3(KV_DIM * C_DIM / 2048), blk, 0, stream>>>(
      wv, wkvb + (size_t)KV_DIM * C_DIM, KV_DIM * C_DIM / 8);
  cvt_f32_bf16<<<dim3(C_DIM * C_DIM / 2048), blk, 0, stream>>>(wo, wob, C_DIM * C_DIM / 8);

  // Projections (m97-structure bf16 MFMA, fp32 out)
  gemm_lds_bf16<<<dim3(C_DIM / 128, M_ROWS / 128), blk, 0, stream>>>(
      xb, wqb, qp, M_ROWS, C_DIM, C_DIM);
  gemm_lds_bf16<<<dim3(2 * KV_DIM / 128, M_ROWS / 128), blk, 0, stream>>>(
      xb, wkvb, kvp, M_ROWS, 2 * KV_DIM, C_DIM);

  // RMSNorm + RoPE -> bf16. Q scale folds 1/sqrt(HD) AND log2(e) (exp2 domain).
  const float qscale = 0.08838834764831845f * 1.4426950408889634f;
  norm_rope_bf16<<<dim3(M_ROWS * NH / 4), blk, 0, stream>>>(
      qp, qb, qw, cost, sint, NH, C_DIM, C_DIM, qscale);
  norm_rope_bf16<<<dim3(M_ROWS * NKV / 4), blk, 0, stream>>>(
      kvp, kb, kw, cost, sint, NKV, 2 * KV_DIM, KV_DIM, 1.0f);

  // V (second half of fused KV) -> transposed bf16 (V^T)
  transpose_v<<<dim3(M_ROWS / 64, KV_DIM / 64), blk, 0, stream>>>(
      kvp + KV_DIM, vt, 2 * KV_DIM);

  // Flash attention: 2048 wave-tasks, 4/block, mirror-paired
  attn_mfma2<<<dim3(512), blk, 0, stream>>>(qb, kb, vt, attb);

  // Output projection
  gemm_lds_bf16<<<dim3(C_DIM / 128, M_ROWS / 128), blk, 0, stream>>>(
      attb, wob, out, M_ROWS, C_DIM, C_DIM);
}